// Round 9
// baseline (306.048 us; speedup 1.0000x reference)
//
#include <hip/hip_runtime.h>
#include <hip/hip_bf16.h>
#include <math.h>

#define T_TOK 2048
#define HDIM  2048
#define IDIM  1408
#define NG    2816          // 2*IDIM
#define NEXP  8
#define NPAIR (T_TOK*2)
#define RPAD  5120          // 4096 rows + per-expert pad-to-128 (max 5112)

typedef __attribute__((ext_vector_type(4))) float  f32x4;
typedef __attribute__((ext_vector_type(4))) short  s16x4;
typedef __attribute__((ext_vector_type(8))) short  s16x8;
typedef __attribute__((ext_vector_type(8))) __bf16 bf16x8;

__device__ __forceinline__ short f2bf(float f) {
  union { float f; unsigned u; } v; v.f = f;
  unsigned r = v.u + 0x7FFFu + ((v.u >> 16) & 1u);   // RNE
  return (short)(r >> 16);
}

__device__ __forceinline__ float bf2f(short s) {
  union { unsigned u; float f; } v; v.u = ((unsigned)(unsigned short)s) << 16;
  return v.f;
}

__device__ __forceinline__ void gload_lds16(const void* g, void* l) {
  __builtin_amdgcn_global_load_lds((const __attribute__((address_space(1))) unsigned int*)g,
                                   (__attribute__((address_space(3))) unsigned int*)l,
                                   16, 0, 0);
}

// ---------------- router ----------------
__global__ void router_kernel(const float* __restrict__ hs, const float* __restrict__ rw,
                              int* __restrict__ pair_e, float* __restrict__ pair_w,
                              int* __restrict__ pair_pos, int* __restrict__ counts) {
  int wid = threadIdx.x >> 6, lane = threadIdx.x & 63;
  int t = blockIdx.x * 4 + wid;
  float acc[NEXP];
#pragma unroll
  for (int e = 0; e < NEXP; e++) acc[e] = 0.f;
  const float* h = hs + (size_t)t * HDIM;
  for (int k = lane; k < HDIM; k += 64) {
    float x = h[k];
    f32x4 w0 = *(const f32x4*)(rw + (size_t)k * NEXP);
    f32x4 w1 = *(const f32x4*)(rw + (size_t)k * NEXP + 4);
#pragma unroll
    for (int e = 0; e < 4; e++) { acc[e] += x * w0[e]; acc[e + 4] += x * w1[e]; }
  }
#pragma unroll
  for (int e = 0; e < NEXP; e++)
#pragma unroll
    for (int off = 32; off > 0; off >>= 1)
      acc[e] += __shfl_xor(acc[e], off, 64);
  if (lane == 0) {
    int i1 = 0; float v1 = acc[0];
#pragma unroll
    for (int e = 1; e < NEXP; e++) if (acc[e] > v1) { v1 = acc[e]; i1 = e; }
    int i2 = -1; float v2 = -3.4e38f;
#pragma unroll
    for (int e = 0; e < NEXP; e++) if (e != i1 && acc[e] > v2) { v2 = acc[e]; i2 = e; }
    float w2 = 1.f / (1.f + expf(v1 - v2));
    float w1 = 1.f - w2;
    int p1 = atomicAdd(&counts[i1], 1);
    int p2 = atomicAdd(&counts[i2], 1);
    pair_e[2*t]   = i1; pair_w[2*t]   = w1; pair_pos[2*t]   = p1;
    pair_e[2*t+1] = i2; pair_w[2*t+1] = w2; pair_pos[2*t+1] = p2;
  }
}

__global__ void prefix_kernel(const int* __restrict__ counts, int* __restrict__ offs) {
  if (threadIdx.x == 0) {
    int s = 0;
    for (int e = 0; e < NEXP; e++) { offs[e] = s; s += (counts[e] + 127) & ~127; }
    offs[NEXP] = s;
  }
}

__global__ void rowmap_kernel(const int* __restrict__ pair_e, const float* __restrict__ pair_w,
                              const int* __restrict__ pair_pos, const int* __restrict__ offs,
                              int* __restrict__ row_token, float* __restrict__ row_weight,
                              int* __restrict__ tok2row) {
  int p = blockIdx.x * 256 + threadIdx.x;
  if (p >= NPAIR) return;
  int e = pair_e[p];
  int row = offs[e] + pair_pos[p];
  row_token[row] = p >> 1;
  row_weight[row] = pair_w[p];
  tok2row[p] = row;
}

// -------- gather tokens -> compact bf16 A, pre-swizzled by (row&7) --------
__global__ __launch_bounds__(256) void gather_kernel(const float* __restrict__ hs,
                                                     const int* __restrict__ row_token,
                                                     short* __restrict__ A_c) {
  int r = blockIdx.x;
  int tok = row_token[r];
  int t = threadIdx.x;
  if (tok < 0) {           // pad row must be zeros
    *(s16x8*)&A_c[(size_t)r * HDIM + t * 8] = (s16x8)0;
    return;
  }
  const float* src = hs + (size_t)tok * HDIM + t * 8;
  f32x4 v0 = *(const f32x4*)src;
  f32x4 v1 = *(const f32x4*)(src + 4);
  s16x8 o;
#pragma unroll
  for (int j = 0; j < 4; j++) { o[j] = f2bf(v0[j]); o[4 + j] = f2bf(v1[j]); }
  int dstg = (t & ~7) | ((t & 7) ^ (r & 7));
  *(s16x8*)&A_c[(size_t)r * HDIM + dstg * 8] = o;
}

// -------- W fp32 [e][K][N] -> bf16 [e][N][K], XOR-swizzled by (n&7) -------
__global__ __launch_bounds__(256) void convert_w_kernel(
    const float* __restrict__ src, short* __restrict__ dst, int K, int N, int e_base) {
  int e = blockIdx.z + e_base;
  src += (size_t)e * K * N;
  dst += (size_t)blockIdx.z * K * N;
  int n0 = blockIdx.x * 64, k0 = blockIdx.y * 64;
  __shared__ short tile[64 * 76];
  int tid = threadIdx.x;
#pragma unroll
  for (int it = 0; it < 4; it++) {
    int s = tid + it * 256;
    int kk = s >> 4, nn = (s & 15) * 4;
    f32x4 v = *(const f32x4*)(src + (size_t)(k0 + kk) * N + n0 + nn);
    s16x4 b;
#pragma unroll
    for (int j = 0; j < 4; j++) b[j] = f2bf(v[j]);
    *(s16x4*)&tile[kk * 76 + nn] = b;
  }
  __syncthreads();
#pragma unroll
  for (int it = 0; it < 2; it++) {
    int s = tid + it * 256;
    int n = s >> 3, g = s & 7;
    int gs = g ^ (n & 7);
    s16x8 o;
#pragma unroll
    for (int j = 0; j < 8; j++) o[j] = tile[(gs * 8 + j) * 76 + n];
    *(s16x8*)&dst[(size_t)(n0 + n) * K + k0 + g * 8] = o;
  }
}

// ===== gate_up GEMM: m97-style, 128M x (64g+64u)N x BK64, 32KB LDS ========
// single-buffered, 2 __syncthreads per K-step, no manual waitcnt;
// latency hiding via 3-5 blocks/CU (m114 implicit wave-level overlap).
__global__ __launch_bounds__(256) void gateup_kernel(
    const short* __restrict__ A_c, const short* __restrict__ W,
    const int* __restrict__ offs, short* __restrict__ S,
    int e_only, size_t w_e_stride) {
  // bijective XCD-chunk remap: 880 = 8 x 110; each XCD gets a contiguous
  // work chunk (rowblock-major) -> A panels + expert B panels L2-local.
  int bid = blockIdx.x;
  int work = (bid & 7) * 110 + (bid >> 3);
  int rblk = work / 22, nb = work % 22;
  int rb = rblk * 128;
  if (rb >= offs[NEXP]) return;
  int e = 0;
#pragma unroll
  for (int i = 1; i < NEXP; i++) e += (rb >= offs[i]);
  if (e_only >= 0 && e != e_only) return;
  const short* Wb = W + (e_only >= 0 ? 0 : (size_t)e * w_e_stride);
  const short* Ar = A_c + (size_t)rb * HDIM;
  const short* Bg = Wb + (size_t)(nb * 64) * HDIM;
  const short* Bu = Wb + (size_t)(IDIM + nb * 64) * HDIM;

  __shared__ short As[128 * 64];        // 16 KB
  __shared__ short Bgs[64 * 64];        // 8 KB
  __shared__ short Bus[64 * 64];        // 8 KB
  int tid = threadIdx.x, lane = tid & 63, wid = tid >> 6;
  int wm = wid >> 1, wn = wid & 1;
  int lm = lane & 15, lg = lane >> 4;

  f32x4 acc[4][4];                      // [mi][nf]; nf 0,1=gate 2,3=up
#pragma unroll
  for (int a = 0; a < 4; a++)
#pragma unroll
    for (int b = 0; b < 4; b++) acc[a][b] = (f32x4)0.f;

  for (int kt = 0; kt < HDIM / 64; kt++) {
    int k0 = kt * 64;
    __syncthreads();                    // prev iteration's LDS reads retired
#pragma unroll
    for (int it = 0; it < 4; it++) {
      int idx = tid + it * 256;
      gload_lds16(Ar + (size_t)(idx >> 3) * HDIM + k0 + (idx & 7) * 8, &As[idx * 8]);
    }
#pragma unroll
    for (int it = 0; it < 2; it++) {
      int idx = tid + it * 256;
      gload_lds16(Bg + (size_t)(idx >> 3) * HDIM + k0 + (idx & 7) * 8, &Bgs[idx * 8]);
      gload_lds16(Bu + (size_t)(idx >> 3) * HDIM + k0 + (idx & 7) * 8, &Bus[idx * 8]);
    }
    __syncthreads();                    // compiler drains vmcnt before barrier
#pragma unroll
    for (int ks = 0; ks < 2; ks++) {
      bf16x8 a[4], bg[2], bu[2];
#pragma unroll
      for (int mi = 0; mi < 4; mi++) {
        int m = wm * 64 + mi * 16 + lm;
        a[mi] = *(const bf16x8*)&As[m * 64 + (((ks * 4 + lg) ^ (m & 7)) * 8)];
      }
#pragma unroll
      for (int j = 0; j < 2; j++) {
        int n = wn * 32 + j * 16 + lm;
        int off = n * 64 + (((ks * 4 + lg) ^ (n & 7)) * 8);
        bg[j] = *(const bf16x8*)&Bgs[off];
        bu[j] = *(const bf16x8*)&Bus[off];
      }
#pragma unroll
      for (int mi = 0; mi < 4; mi++)
#pragma unroll
        for (int j = 0; j < 2; j++) {
          acc[mi][j]     = __builtin_amdgcn_mfma_f32_16x16x32_bf16(a[mi], bg[j], acc[mi][j], 0, 0, 0);
          acc[mi][2 + j] = __builtin_amdgcn_mfma_f32_16x16x32_bf16(a[mi], bu[j], acc[mi][2 + j], 0, 0, 0);
        }
    }
  }
  // epilogue: SiLU(gate)*up -> S (bf16, granule-swizzled by rg&7 per 64 cols)
#pragma unroll
  for (int mi = 0; mi < 4; mi++)
#pragma unroll
    for (int j = 0; j < 2; j++)
#pragma unroll
      for (int jj = 0; jj < 4; jj++) {
        int row = wm * 64 + mi * 16 + lg * 4 + jj;
        int rg = rb + row;
        int o = wn * 32 + j * 16 + lm;
        int dc = (((o >> 3) ^ (rg & 7)) << 3) | (o & 7);
        float g = acc[mi][j][jj], u = acc[mi][2 + j][jj];
        float sv = (g / (1.f + expf(-g))) * u;
        S[(size_t)rg * IDIM + nb * 64 + dc] = f2bf(sv);
      }
}

// ===== down GEMM: m97-style, 128M x 128N x BK64, 32KB LDS =================
__global__ __launch_bounds__(256) void down_kernel(
    const short* __restrict__ S, const short* __restrict__ W,
    const int* __restrict__ offs, short* __restrict__ Sout,
    int e_only, size_t w_e_stride) {
  int bid = blockIdx.x;                 // 640 = 8 x 80
  int work = (bid & 7) * 80 + (bid >> 3);
  int rblk = work / 16, nb = work % 16;
  int rb = rblk * 128;
  if (rb >= offs[NEXP]) return;
  int e = 0;
#pragma unroll
  for (int i = 1; i < NEXP; i++) e += (rb >= offs[i]);
  if (e_only >= 0 && e != e_only) return;
  const short* Ar = S + (size_t)rb * IDIM;
  const short* Bw = W + (e_only >= 0 ? 0 : (size_t)e * w_e_stride) + (size_t)(nb * 128) * IDIM;

  __shared__ short As[128 * 64];        // 16 KB
  __shared__ short Bs[128 * 64];        // 16 KB
  int tid = threadIdx.x, lane = tid & 63, wid = tid >> 6;
  int wm = wid >> 1, wn = wid & 1;
  int lm = lane & 15, lg = lane >> 4;

  f32x4 acc[4][4];
#pragma unroll
  for (int a = 0; a < 4; a++)
#pragma unroll
    for (int b = 0; b < 4; b++) acc[a][b] = (f32x4)0.f;

  for (int kt = 0; kt < IDIM / 64; kt++) {   // 22 steps
    int k0 = kt * 64;
    __syncthreads();
#pragma unroll
    for (int it = 0; it < 4; it++) {
      int idx = tid + it * 256;
      gload_lds16(Ar + (size_t)(idx >> 3) * IDIM + k0 + (idx & 7) * 8, &As[idx * 8]);
      gload_lds16(Bw + (size_t)(idx >> 3) * IDIM + k0 + (idx & 7) * 8, &Bs[idx * 8]);
    }
    __syncthreads();
#pragma unroll
    for (int ks = 0; ks < 2; ks++) {
      bf16x8 a[4], b[4];
#pragma unroll
      for (int mi = 0; mi < 4; mi++) {
        int m = wm * 64 + mi * 16 + lm;
        a[mi] = *(const bf16x8*)&As[m * 64 + (((ks * 4 + lg) ^ (m & 7)) * 8)];
      }
#pragma unroll
      for (int nf = 0; nf < 4; nf++) {
        int n = wn * 64 + nf * 16 + lm;
        b[nf] = *(const bf16x8*)&Bs[n * 64 + (((ks * 4 + lg) ^ (n & 7)) * 8)];
      }
#pragma unroll
      for (int mi = 0; mi < 4; mi++)
#pragma unroll
        for (int nf = 0; nf < 4; nf++)
          acc[mi][nf] = __builtin_amdgcn_mfma_f32_16x16x32_bf16(a[mi], b[nf], acc[mi][nf], 0, 0, 0);
    }
  }
  // epilogue: plain bf16 stores (combine does the weighted sum)
#pragma unroll
  for (int mi = 0; mi < 4; mi++)
#pragma unroll
    for (int nf = 0; nf < 4; nf++)
#pragma unroll
      for (int jj = 0; jj < 4; jj++) {
        int row = wm * 64 + mi * 16 + lg * 4 + jj;
        int col = nb * 128 + wn * 64 + nf * 16 + lm;
        Sout[(size_t)(rb + row) * HDIM + col] = f2bf(acc[mi][nf][jj]);
      }
}

// ------------- combine: out[t] = w1*Sout[r1] + w2*Sout[r2] ---------------
__global__ __launch_bounds__(256) void combine_kernel(
    const short* __restrict__ Sout, const int* __restrict__ tok2row,
    const float* __restrict__ row_weight, float* __restrict__ out) {
  int t = blockIdx.x;
  int r1 = tok2row[2 * t], r2 = tok2row[2 * t + 1];
  float w1 = row_weight[r1], w2 = row_weight[r2];
  int c = threadIdx.x * 8;
  s16x8 a = *(const s16x8*)&Sout[(size_t)r1 * HDIM + c];
  s16x8 b = *(const s16x8*)&Sout[(size_t)r2 * HDIM + c];
  float* o = out + (size_t)t * HDIM + c;
#pragma unroll
  for (int j = 0; j < 8; j++) o[j] = w1 * bf2f(a[j]) + w2 * bf2f(b[j]);
}

extern "C" void kernel_launch(void* const* d_in, const int* in_sizes, int n_in,
                              void* d_out, int out_size, void* d_ws, size_t ws_size,
                              hipStream_t stream) {
  const float* hs  = (const float*)d_in[0];
  const float* rw  = (const float*)d_in[1];
  const float* guw = (const float*)d_in[2];
  const float* dw  = (const float*)d_in[3];
  float* out = (float*)d_out;

  char* ws = (char*)d_ws;
  size_t off = 0;
  auto take = [&](size_t b) { size_t p = off; off = (off + b + 255) & ~(size_t)255; return p; };
  size_t s_off      = take((size_t)RPAD * IDIM * 2);   // 14.4 MB
  int*   counts     = (int*)(ws + take(32 * 4));
  int*   offs       = (int*)(ws + take(16 * 4));
  int*   pair_e     = (int*)(ws + take(NPAIR * 4));
  float* pair_w     = (float*)(ws + take(NPAIR * 4));
  int*   pair_pos   = (int*)(ws + take(NPAIR * 4));
  int*   row_token  = (int*)(ws + take(RPAD * 4));
  float* row_weight = (float*)(ws + take(RPAD * 4));
  int*   tok2row    = (int*)(ws + take(NPAIR * 4));
  size_t ac_off     = take((size_t)RPAD * HDIM * 2);   // 21.0 MB
  size_t wg_off     = off;                             // Wg (Wd overlays later)

  short* S    = (short*)(ws + s_off);
  short* A_c  = (short*)(ws + ac_off);

  const size_t WG_BYTES = (size_t)NEXP * NG * HDIM * 2;   // 92.3 MB
  const size_t SOUT_BYTES = (size_t)RPAD * HDIM * 2;      // 21.0 MB
  bool full = ws_size >= wg_off + WG_BYTES + SOUT_BYTES;

  hipMemsetAsync(counts, 0, 32 * 4, stream);
  hipMemsetAsync(row_token, 0xFF, RPAD * 4, stream);

  router_kernel<<<T_TOK / 4, 256, 0, stream>>>(hs, rw, pair_e, pair_w, pair_pos, counts);
  prefix_kernel<<<1, 64, 0, stream>>>(counts, offs);
  rowmap_kernel<<<NPAIR / 256, 256, 0, stream>>>(pair_e, pair_w, pair_pos, offs,
                                                 row_token, row_weight, tok2row);
  gather_kernel<<<RPAD, 256, 0, stream>>>(hs, row_token, A_c);

  if (full) {
    short* Wg   = (short*)(ws + wg_off);
    short* Wd   = (short*)(ws + wg_off);                 // overlays Wg (dead after gateup)
    short* Sout = (short*)(ws + wg_off + WG_BYTES);
    convert_w_kernel<<<dim3(NG / 64, HDIM / 64, NEXP), 256, 0, stream>>>(guw, Wg, HDIM, NG, 0);
    gateup_kernel<<<880, 256, 0, stream>>>(A_c, Wg, offs, S, -1, (size_t)NG * HDIM);
    convert_w_kernel<<<dim3(HDIM / 64, IDIM / 64, NEXP), 256, 0, stream>>>(dw, Wd, IDIM, HDIM, 0);
    down_kernel<<<640, 256, 0, stream>>>(S, Wd, offs, Sout, -1, (size_t)HDIM * IDIM);
    combine_kernel<<<T_TOK, 256, 0, stream>>>(Sout, tok2row, row_weight, out);
  } else {
    short* slot = (short*)(ws + wg_off);                 // 11.5 MB
    short* Sout = (short*)(ws + wg_off + ((size_t)12 << 20));
    for (int e = 0; e < NEXP; e++) {
      convert_w_kernel<<<dim3(NG / 64, HDIM / 64, 1), 256, 0, stream>>>(guw, slot, HDIM, NG, e);
      gateup_kernel<<<880, 256, 0, stream>>>(A_c, slot, offs, S, e, 0);
    }
    for (int e = 0; e < NEXP; e++) {
      convert_w_kernel<<<dim3(HDIM / 64, IDIM / 64, 1), 256, 0, stream>>>(dw, slot, IDIM, HDIM, e);
      down_kernel<<<640, 256, 0, stream>>>(S, slot, offs, Sout, e, 0);
    }
    combine_kernel<<<T_TOK, 256, 0, stream>>>(Sout, tok2row, row_weight, out);
  }
}